// Round 1
// baseline (146.801 us; speedup 1.0000x reference)
//
#include <hip/hip_runtime.h>

typedef unsigned int uint;
typedef unsigned short ushort;
typedef __attribute__((ext_vector_type(4))) float f32x4;
typedef __attribute__((ext_vector_type(8))) short short8;

#define BM 64
#define BN 256
#define BK 64
#define KTOT 2048
#define NSTEP (KTOT / BK)

__device__ __forceinline__ ushort f2bf(float f) {
    uint u = __builtin_bit_cast(uint, f);
    u += 0x7FFFu + ((u >> 16) & 1u);   // round-to-nearest-even
    return (ushort)(u >> 16);
}

// ---- kernel 1: ftime[b][k] = b_proj[k] + sum_t silu(c[b,t]) * W_proj[k,t]
__global__ __launch_bounds__(256) void k_ftime(const float* __restrict__ c,
                                               const float* __restrict__ Wp,
                                               const float* __restrict__ bp,
                                               float* __restrict__ ftime) {
    int blk = blockIdx.x;            // 0..127 : b*16+k
    int b = blk >> 4, k = blk & 15;
    int tid = threadIdx.x;
    const float* cb = c + b * 1024;
    const float* wk = Wp + k * 1024;
    float v = 0.f;
    for (int t = tid; t < 1024; t += 256) {
        float z = cb[t];
        v += (z / (1.f + expf(-z))) * wk[t];
    }
    for (int off = 32; off; off >>= 1) v += __shfl_down(v, off);
    __shared__ float red[4];
    if ((tid & 63) == 0) red[tid >> 6] = v;
    __syncthreads();
    if (tid == 0) ftime[blk] = red[0] + red[1] + red[2] + red[3] + bp[k];
}

// ---- kernel 2: g[b][r] = (1/16) sum_k ftime[b][k] * cos(pi*k*r/8)
__global__ __launch_bounds__(128) void k_g(const float* __restrict__ ftime,
                                           float* __restrict__ g) {
    int t = threadIdx.x;             // 0..127
    int b = t >> 4, r = t & 15;
    float s = 0.f;
    for (int k = 0; k < 16; ++k)
        s += ftime[b * 16 + k] * cosf((float)((k * r) & 15) * 0.39269908169872414f);
    g[t] = s * 0.0625f;
}

// ---- kernel 3: W_lin fp32 -> bf16 (into workspace)
__global__ __launch_bounds__(256) void k_wcvt(const float* __restrict__ W,
                                              ushort* __restrict__ o) {
    int i = (blockIdx.x * 256 + threadIdx.x) * 4;
    float4 v = *(const float4*)(W + i);
    uint lo = (uint)f2bf(v.x) | ((uint)f2bf(v.y) << 16);
    uint hi = (uint)f2bf(v.z) | ((uint)f2bf(v.w) << 16);
    *(uint2*)(o + i) = make_uint2(lo, hi);
}

// ---- kernel 4: fused modulate + GEMM
// out[m, o] = scale[o] * ( sum_w xm[m,w] * W_lin[o,w] + b_lin[o] )
// xm within each 4x4 patch: circular conv with g  (16x16 circulant)
__global__ __launch_bounds__(512, 4) void k_gemm(
    const float* __restrict__ x,
    const float* __restrict__ Wl,     // fp32 W_lin (fallback)
    const ushort* __restrict__ Wb,    // bf16 W_lin (preferred, may be null)
    const float* __restrict__ blin,
    const float* __restrict__ szv,
    const float* __restrict__ g_ws,
    float* __restrict__ out,
    int use_wb) {

    __shared__ __align__(16) ushort As[BM * BK];   // 8 KB  (swizzled)
    __shared__ __align__(16) ushort Bs[BN * BK];   // 32 KB (swizzled)

    const int tid = threadIdx.x;
    const int lane = tid & 63;
    const int wid = tid >> 6;           // 0..7
    const int m0 = blockIdx.x * BM;
    const int b = m0 >> 12;             // 4096 rows per batch

    float gv[16];
#pragma unroll
    for (int r = 0; r < 16; ++r) gv[r] = g_ws[b * 16 + r];

    const int wr = wid >> 2;            // 0..1 : 32-row strip
    const int wc = wid & 3;             // 0..3 : 64-col strip

    f32x4 acc[2][4];
#pragma unroll
    for (int i = 0; i < 2; ++i)
#pragma unroll
        for (int j = 0; j < 4; ++j) acc[i][j] = (f32x4)0.f;

    const int a_hp = (tid & 255) >> 4;  // patch row 0..15
    const int a_wp = tid & 15;          // patch col 0..15

    for (int kt = 0; kt < NSTEP; ++kt) {
        const int k0g = kt * BK;
        if (tid < 256) {
            // ---- modulate one 4x4 patch of x into bf16 A-tile
            const float* xr = x + (size_t)(m0 + 4 * a_hp) * 2048 + k0g + 4 * a_wp;
            float4 r0 = *(const float4*)(xr);
            float4 r1 = *(const float4*)(xr + 2048);
            float4 r2 = *(const float4*)(xr + 4096);
            float4 r3 = *(const float4*)(xr + 6144);
            float xin[16] = {r0.x, r0.y, r0.z, r0.w, r1.x, r1.y, r1.z, r1.w,
                             r2.x, r2.y, r2.z, r2.w, r3.x, r3.y, r3.z, r3.w};
            float xo[16];
#pragma unroll
            for (int n = 0; n < 16; ++n) {
                float s = 0.f;
#pragma unroll
                for (int m = 0; m < 16; ++m) s += gv[(n - m) & 15] * xin[m];
                xo[n] = s;
            }
#pragma unroll
            for (int i = 0; i < 4; ++i) {
                int row = 4 * a_hp + i;
                uint lo = (uint)f2bf(xo[i * 4 + 0]) | ((uint)f2bf(xo[i * 4 + 1]) << 16);
                uint hi = (uint)f2bf(xo[i * 4 + 2]) | ((uint)f2bf(xo[i * 4 + 3]) << 16);
                int off = row * (BK * 2) + ((a_wp * 8) ^ ((row & 7) << 4));
                *(uint2*)((char*)As + off) = make_uint2(lo, hi);
            }
        } else {
            const int tt = tid - 256;   // 0..255
            if (use_wb) {
#pragma unroll
                for (int it = 0; it < 8; ++it) {
                    int chunk = it * 256 + tt;   // 0..2047
                    int row = chunk >> 3;        // 0..255
                    int c8 = chunk & 7;
                    short8 v = *(const short8*)(Wb + (size_t)row * 2048 + k0g + c8 * 8);
                    int off = row * (BK * 2) + ((c8 * 16) ^ ((row & 7) << 4));
                    *(short8*)((char*)Bs + off) = v;
                }
            } else {
#pragma unroll
                for (int it = 0; it < 16; ++it) {
                    int chunk = it * 256 + tt;   // 0..4095
                    int row = chunk >> 4;
                    int c4 = chunk & 15;
                    float4 v = *(const float4*)(Wl + (size_t)row * 2048 + k0g + c4 * 4);
                    uint lo = (uint)f2bf(v.x) | ((uint)f2bf(v.y) << 16);
                    uint hi = (uint)f2bf(v.z) | ((uint)f2bf(v.w) << 16);
                    int off = row * (BK * 2) + ((c4 * 8) ^ ((row & 7) << 4));
                    *(uint2*)((char*)Bs + off) = make_uint2(lo, hi);
                }
            }
        }
        __syncthreads();

#pragma unroll
        for (int kk = 0; kk < 2; ++kk) {
            const int k0 = kk * 32 + ((lane >> 4) << 3);
            short8 a[2], bb[4];
#pragma unroll
            for (int mf = 0; mf < 2; ++mf) {
                int r = wr * 32 + mf * 16 + (lane & 15);
                int off = r * (BK * 2) + (((k0 * 2)) ^ ((r & 7) << 4));
                a[mf] = *(const short8*)((const char*)As + off);
            }
#pragma unroll
            for (int nf = 0; nf < 4; ++nf) {
                int r = wc * 64 + nf * 16 + (lane & 15);
                int off = r * (BK * 2) + (((k0 * 2)) ^ ((r & 7) << 4));
                bb[nf] = *(const short8*)((const char*)Bs + off);
            }
#pragma unroll
            for (int mf = 0; mf < 2; ++mf)
#pragma unroll
                for (int nf = 0; nf < 4; ++nf)
                    acc[mf][nf] = __builtin_amdgcn_mfma_f32_16x16x32_bf16(
                        a[mf], bb[nf], acc[mf][nf], 0, 0, 0);
        }
        __syncthreads();
    }

    // ---- epilogue: out = scale * (acc + b_lin)
#pragma unroll
    for (int nf = 0; nf < 4; ++nf) {
        int col = wc * 64 + nf * 16 + (lane & 15);
        float scale = szv[col] * 45.254833995939045f;  // sqrt(2048)
        float bl = blin[col];
#pragma unroll
        for (int mf = 0; mf < 2; ++mf) {
            int row = m0 + wr * 32 + mf * 16 + ((lane >> 4) << 2);
#pragma unroll
            for (int j = 0; j < 4; ++j)
                out[(size_t)(row + j) * 256 + col] = scale * (acc[mf][nf][j] + bl);
        }
    }
}

extern "C" void kernel_launch(void* const* d_in, const int* in_sizes, int n_in,
                              void* d_out, int out_size, void* d_ws, size_t ws_size,
                              hipStream_t stream) {
    const float* x  = (const float*)d_in[0];   // (8, 4096, 2048)
    const float* c  = (const float*)d_in[1];   // (8, 1024)
    const float* Wp = (const float*)d_in[2];   // (16, 1024)
    const float* bp = (const float*)d_in[3];   // (16,)
    const float* Wl = (const float*)d_in[4];   // (256, 2048)
    const float* bl = (const float*)d_in[5];   // (256,)
    const float* sz = (const float*)d_in[6];   // (256,)
    float* out = (float*)d_out;

    float* wsf = (float*)d_ws;
    float* ftime = wsf;          // 128 floats
    float* g = wsf + 128;        // 128 floats
    ushort* wbf = (ushort*)(wsf + 256);
    size_t need = 256 * sizeof(float) + (size_t)256 * 2048 * sizeof(ushort);
    int use_wb = (ws_size >= need) ? 1 : 0;

    k_ftime<<<128, 256, 0, stream>>>(c, Wp, bp, ftime);
    k_g<<<1, 128, 0, stream>>>(ftime, g);
    if (use_wb) k_wcvt<<<512, 256, 0, stream>>>(Wl, wbf);
    k_gemm<<<512, 512, 0, stream>>>(x, Wl, use_wb ? wbf : (const ushort*)nullptr,
                                    bl, sz, g, out, use_wb);
}